// Round 4
// baseline (404.233 us; speedup 1.0000x reference)
//
#include <hip/hip_runtime.h>
#include <math.h>

#define B_   64
#define T_   2000
#define ENC_ 512
#define QD_  1024
#define U_   128
#define F_   32
#define KW_  31

typedef __bf16 bf16x8 __attribute__((ext_vector_type(8)));
typedef float  f32x4  __attribute__((ext_vector_type(4)));

__device__ __forceinline__ __bf16 f2bf(float f) { return (__bf16)f; }

// ---------------------------------------------------------------------------
// prep: fused weight-prep.
//  blocks 0..63   : bias[b,u] = query[b,:]@Wq[:,u] + conv_b@Wloc[:,u] + b_a[u]
//  blocks 64..97  : wsB = bf16 B-operand in MFMA fragment order
//    wsB layout [17 kk][8 nt][64 lane][8 bf16]; kk<16 = W_keys 32-K slices,
//    kk=16 = CW[k,u] = sum_f conv_w[k,f]*Wloc[f,u] (k<31, zero-pad to 32).
//    lane l holds B[k = kk*32 + (l>>4)*8 + j][n = nt*16 + (l&15)].
// ---------------------------------------------------------------------------
__global__ __launch_bounds__(256)
void prep(const float* __restrict__ query, const float* __restrict__ Wq,
          const float* __restrict__ conv_b, const float* __restrict__ Wloc,
          const float* __restrict__ b_a, const float* __restrict__ Wk,
          const float* __restrict__ conv_w,
          float* __restrict__ bias, __bf16* __restrict__ wsB)
{
    const int tid = threadIdx.x;
    if (blockIdx.x < 64) {
        // ----- bias role -----
        int b = blockIdx.x;
        int u = tid & 127;
        int h = tid >> 7;                    // 0..1, K-half of 512
        const float* qr = query + b * QD_ + h * 512;
        const float* wq = Wq + (size_t)(h * 512) * U_ + u;
        float a0 = 0.f, a1 = 0.f, a2 = 0.f, a3 = 0.f;
        for (int e = 0; e < 512; e += 4) {
            a0 = fmaf(qr[e + 0], wq[(size_t)(e + 0) * U_], a0);
            a1 = fmaf(qr[e + 1], wq[(size_t)(e + 1) * U_], a1);
            a2 = fmaf(qr[e + 2], wq[(size_t)(e + 2) * U_], a2);
            a3 = fmaf(qr[e + 3], wq[(size_t)(e + 3) * U_], a3);
        }
        __shared__ float red[256];
        red[tid] = (a0 + a1) + (a2 + a3);
        __syncthreads();
        if (h == 0) {
            float s = red[u] + red[128 + u];
            float cb = 0.f;
            for (int f = 0; f < F_; ++f)
                cb = fmaf(conv_b[f], Wloc[f * U_ + u], cb);
            bias[b * U_ + u] = s + cb + b_a[u];
        }
    } else {
        // ----- wsB role -----
        int idx = (blockIdx.x - 64) * 256 + tid;     // 0 .. 17*8*64-1
        if (idx >= 17 * 8 * 64) return;
        int lane = idx & 63;
        int nt   = (idx >> 6) & 7;
        int kk   = idx >> 9;
        int n = nt * 16 + (lane & 15);
        int kbase = (lane >> 4) * 8;
        float vals[8];
        if (kk < 16) {
            #pragma unroll
            for (int j = 0; j < 8; ++j)
                vals[j] = Wk[(size_t)(kk * 32 + kbase + j) * U_ + n];
        } else {
            #pragma unroll
            for (int j = 0; j < 8; ++j) {
                int k = kbase + j;
                float s = 0.f;
                if (k < KW_)
                    for (int f = 0; f < F_; ++f)
                        s = fmaf(conv_w[k * F_ + f], Wloc[f * U_ + n], s);
                vals[j] = s;
            }
        }
        __bf16* dst = wsB + (size_t)idx * 8;
        #pragma unroll
        for (int j = 0; j < 8; ++j) dst[j] = f2bf(vals[j]);
    }
}

// ---------------------------------------------------------------------------
// lsa_energy: energy[b,t] = v . tanh(memory[b,t,:]@Wk + prevwin@CW + bias[b,:])
// grid: 64*16 blocks of 256 threads; block = 128 rows; wave = 32 rows x 128 U.
// Fully-masked tiles (t0 >= seqlen[b]) exit before touching memory.
// Distance-1 software pipeline on K: next A-tile loads issue before current
// MFMAs. Nontemporal loads: memory is streamed exactly once (spare L2 for wsB).
// ---------------------------------------------------------------------------
__global__ __launch_bounds__(256, 4)
void lsa_energy(const float* __restrict__ mem, const float* __restrict__ prev,
                const float* __restrict__ bias, const bf16x8* __restrict__ wsB,
                const float* __restrict__ v_a, const int* __restrict__ seqlen,
                float* __restrict__ energy)
{
    const int tile = blockIdx.x & 15;
    const int b    = blockIdx.x >> 4;
    const int t0   = tile * 128;
    if (t0 >= seqlen[b]) return;         // masked tile: softmax forces -1e9

    const int tid  = threadIdx.x;
    const int wave = tid >> 6;
    const int lane = tid & 63;
    const int l15  = lane & 15;
    const int quad = lane >> 4;

    __shared__ float lds_prev[160];      // prev[b, t0-15+i], zero-padded
    __shared__ float lds_bias[U_];
    __shared__ float lds_v[U_];

    if (tid < 160) {
        int t = t0 - 15 + tid;
        float v = 0.f;
        if (tid < 158 && t >= 0 && t < T_) v = prev[b * T_ + t];
        lds_prev[tid] = v;
    }
    if (tid < U_)                 lds_bias[tid] = bias[b * U_ + tid];
    if (tid >= U_ && tid < 2*U_)  lds_v[tid - U_] = v_a[tid - U_];
    __syncthreads();

    f32x4 acc[2][8];
    #pragma unroll
    for (int s = 0; s < 2; ++s)
        #pragma unroll
        for (int n = 0; n < 8; ++n) acc[s][n] = (f32x4){0.f, 0.f, 0.f, 0.f};

    const int rl0 = wave * 32 + l15;                      // local row, s=0
    int r0 = t0 + rl0;      if (r0 > T_ - 1) r0 = T_ - 1; // clamp tail tile
    int r1 = t0 + rl0 + 16; if (r1 > T_ - 1) r1 = T_ - 1;
    const float* pA0 = mem + ((size_t)b * T_ + r0) * ENC_ + quad * 8;
    const float* pA1 = mem + ((size_t)b * T_ + r1) * ENC_ + quad * 8;
    const bf16x8* bp = wsB + lane;                        // bump 8*64 per kk

    // pipeline prologue: kk=0 A-tile
    f32x4 x0 = __builtin_nontemporal_load((const f32x4*)pA0);
    f32x4 y0 = __builtin_nontemporal_load((const f32x4*)(pA0 + 4));
    f32x4 x1 = __builtin_nontemporal_load((const f32x4*)pA1);
    f32x4 y1 = __builtin_nontemporal_load((const f32x4*)(pA1 + 4));

    for (int kk = 0; kk < 16; ++kk) {
        // B group 1 loads first (L2 hits, short latency)
        bf16x8 bfr[4];
        #pragma unroll
        for (int n = 0; n < 4; ++n) bfr[n] = bp[n * 64];

        // prefetch next A-tile (HBM, long latency) before any MFMA
        f32x4 nx0, ny0, nx1, ny1;
        if (kk < 15) {
            const float* q0 = pA0 + (kk + 1) * 32;
            const float* q1 = pA1 + (kk + 1) * 32;
            nx0 = __builtin_nontemporal_load((const f32x4*)q0);
            ny0 = __builtin_nontemporal_load((const f32x4*)(q0 + 4));
            nx1 = __builtin_nontemporal_load((const f32x4*)q1);
            ny1 = __builtin_nontemporal_load((const f32x4*)(q1 + 4));
        }

        bf16x8 a0, a1;
        #pragma unroll
        for (int j = 0; j < 4; ++j) { a0[j] = f2bf(x0[j]); a0[4+j] = f2bf(y0[j]); }
        #pragma unroll
        for (int j = 0; j < 4; ++j) { a1[j] = f2bf(x1[j]); a1[4+j] = f2bf(y1[j]); }

        #pragma unroll
        for (int n = 0; n < 4; ++n) {
            acc[0][n] = __builtin_amdgcn_mfma_f32_16x16x32_bf16(a0, bfr[n], acc[0][n], 0, 0, 0);
            acc[1][n] = __builtin_amdgcn_mfma_f32_16x16x32_bf16(a1, bfr[n], acc[1][n], 0, 0, 0);
        }
        #pragma unroll
        for (int n = 0; n < 4; ++n) bfr[n] = bp[(n + 4) * 64];
        #pragma unroll
        for (int n = 0; n < 4; ++n) {
            acc[0][n+4] = __builtin_amdgcn_mfma_f32_16x16x32_bf16(a0, bfr[n], acc[0][n+4], 0, 0, 0);
            acc[1][n+4] = __builtin_amdgcn_mfma_f32_16x16x32_bf16(a1, bfr[n], acc[1][n+4], 0, 0, 0);
        }
        bp += 8 * 64;
        x0 = nx0; y0 = ny0; x1 = nx1; y1 = ny1;
    }

    // location conv as one K=32 MFMA step (CW slice kk=16); A from prev window
    {
        bf16x8 a0, a1;
        int base = rl0 + quad * 8;   // lds_prev idx = row_local + k
        #pragma unroll
        for (int j = 0; j < 8; ++j) a0[j] = f2bf(lds_prev[base + j]);
        #pragma unroll
        for (int j = 0; j < 8; ++j) a1[j] = f2bf(lds_prev[base + 16 + j]);
        bf16x8 bfr[4];
        #pragma unroll
        for (int n = 0; n < 4; ++n) bfr[n] = bp[n * 64];
        #pragma unroll
        for (int n = 0; n < 4; ++n) {
            acc[0][n] = __builtin_amdgcn_mfma_f32_16x16x32_bf16(a0, bfr[n], acc[0][n], 0, 0, 0);
            acc[1][n] = __builtin_amdgcn_mfma_f32_16x16x32_bf16(a1, bfr[n], acc[1][n], 0, 0, 0);
        }
        #pragma unroll
        for (int n = 0; n < 4; ++n) bfr[n] = bp[(n + 4) * 64];
        #pragma unroll
        for (int n = 0; n < 4; ++n) {
            acc[0][n+4] = __builtin_amdgcn_mfma_f32_16x16x32_bf16(a0, bfr[n], acc[0][n+4], 0, 0, 0);
            acc[1][n+4] = __builtin_amdgcn_mfma_f32_16x16x32_bf16(a1, bfr[n], acc[1][n+4], 0, 0, 0);
        }
    }

    // epilogue: tanh(x + bias) * v, dot over 128 cols
    float part[2][4] = {{0.f,0.f,0.f,0.f},{0.f,0.f,0.f,0.f}};
    #pragma unroll
    for (int n = 0; n < 8; ++n) {
        float bb = lds_bias[n * 16 + l15];
        float vv = lds_v[n * 16 + l15];
        #pragma unroll
        for (int s = 0; s < 2; ++s)
            #pragma unroll
            for (int i = 0; i < 4; ++i) {
                float x  = acc[s][n][i] + bb;
                float ax = __builtin_fabsf(x);
                float e  = __expf(-2.f * ax);
                float th = (1.f - e) / (1.f + e);     // tanh(|x|), no overflow
                part[s][i] += (x < 0.f ? -th : th) * vv;
            }
    }
    #pragma unroll
    for (int s = 0; s < 2; ++s)
        #pragma unroll
        for (int i = 0; i < 4; ++i) {
            float p = part[s][i];
            p += __shfl_xor(p, 1);
            p += __shfl_xor(p, 2);
            p += __shfl_xor(p, 4);
            p += __shfl_xor(p, 8);       // butterfly within 16-lane group
            part[s][i] = p;
        }
    if (l15 == 0) {
        #pragma unroll
        for (int s = 0; s < 2; ++s)
            #pragma unroll
            for (int i = 0; i < 4; ++i) {
                int t = t0 + wave * 32 + s * 16 + quad * 4 + i;
                if (t < T_) energy[b * T_ + t] = part[s][i];
            }
    }
}

// ---------------------------------------------------------------------------
// softmax over T with length mask; out[0] = alignments, out[1] = align + prev.
// Energy was written into out[0] region as scratch; in-place per block.
// ---------------------------------------------------------------------------
__global__ __launch_bounds__(256)
void lsa_softmax(const float* __restrict__ prev, const int* __restrict__ seqlen,
                 float* __restrict__ out)
{
    int b = blockIdx.x;
    int tid = threadIdx.x;
    int len = seqlen[b];
    float e[8];
    float m = -1e30f;
    #pragma unroll
    for (int i = 0; i < 8; ++i) {
        int t = tid + i * 256;
        float x = -1e30f;
        if (t < T_) {
            x = out[b * T_ + t];
            if (t >= len) x = -1e9f;
        }
        e[i] = x;
        m = fmaxf(m, x);
    }
    #pragma unroll
    for (int off = 32; off >= 1; off >>= 1) m = fmaxf(m, __shfl_xor(m, off));
    __shared__ float wmax[4], wsum[4];
    if ((tid & 63) == 0) wmax[tid >> 6] = m;
    __syncthreads();
    m = fmaxf(fmaxf(wmax[0], wmax[1]), fmaxf(wmax[2], wmax[3]));
    float s = 0.f;
    #pragma unroll
    for (int i = 0; i < 8; ++i) {
        float p = __expf(e[i] - m);
        if (tid + i * 256 >= T_) p = 0.f;
        e[i] = p;
        s += p;
    }
    #pragma unroll
    for (int off = 32; off >= 1; off >>= 1) s += __shfl_xor(s, off);
    if ((tid & 63) == 0) wsum[tid >> 6] = s;
    __syncthreads();
    s = wsum[0] + wsum[1] + wsum[2] + wsum[3];
    float inv = 1.f / s;
    #pragma unroll
    for (int i = 0; i < 8; ++i) {
        int t = tid + i * 256;
        if (t < T_) {
            float a = e[i] * inv;
            out[b * T_ + t] = a;
            out[(size_t)B_ * T_ + b * T_ + t] = a + prev[b * T_ + t];
        }
    }
}

// ---------------------------------------------------------------------------
extern "C" void kernel_launch(void* const* d_in, const int* in_sizes, int n_in,
                              void* d_out, int out_size, void* d_ws, size_t ws_size,
                              hipStream_t stream)
{
    const float* query  = (const float*)d_in[0];
    const float* prev   = (const float*)d_in[1];
    const float* memory = (const float*)d_in[2];
    const int*   mlen   = (const int*)d_in[3];
    const float* Wq     = (const float*)d_in[4];
    const float* Wk     = (const float*)d_in[5];
    const float* conv_w = (const float*)d_in[6];
    const float* conv_b = (const float*)d_in[7];
    const float* Wloc   = (const float*)d_in[8];
    const float* v_a    = (const float*)d_in[9];
    const float* b_a    = (const float*)d_in[10];
    float* out = (float*)d_out;

    // ws: [wsB: 17*8*64*8 bf16 = 139264 B][bias: 64*128 f32 = 32768 B]
    __bf16* wsB  = (__bf16*)d_ws;
    float*  bias = (float*)((char*)d_ws + (size_t)17 * 8 * 64 * 8 * 2);

    prep<<<dim3(98), dim3(256), 0, stream>>>(query, Wq, conv_b, Wloc, b_a,
                                             Wk, conv_w, bias, wsB);
    lsa_energy<<<dim3(64 * 16), dim3(256), 0, stream>>>(memory, prev, bias,
                                                        (const bf16x8*)wsB,
                                                        v_a, mlen, out);
    lsa_softmax<<<dim3(64), dim3(256), 0, stream>>>(prev, mlen, out);
}

// Round 5
// 399.800 us; speedup vs baseline: 1.0111x; 1.0111x over previous
//
#include <hip/hip_runtime.h>
#include <math.h>

#define B_   64
#define T_   2000
#define ENC_ 512
#define QD_  1024
#define U_   128
#define F_   32
#define KW_  31

typedef __bf16 bf16x8 __attribute__((ext_vector_type(8)));
typedef float  f32x4  __attribute__((ext_vector_type(4)));

__device__ __forceinline__ __bf16 f2bf(float f) { return (__bf16)f; }

// ---------------------------------------------------------------------------
// prep: fused weight-prep.
//  blocks 0..63   : bias[b,u] = query[b,:]@Wq[:,u] + conv_b@Wloc[:,u] + b_a[u]
//  blocks 64..97  : wsB = bf16 B-operand in MFMA fragment order
//    wsB layout [17 kk][8 nt][64 lane][8 bf16]; kk<16 = W_keys 32-K slices,
//    kk=16 = CW[k,u] = sum_f conv_w[k,f]*Wloc[f,u] (k<31, zero-pad to 32).
//    lane l holds B[k = kk*32 + (l>>4)*8 + j][n = nt*16 + (l&15)].
// ---------------------------------------------------------------------------
__global__ __launch_bounds__(256)
void prep(const float* __restrict__ query, const float* __restrict__ Wq,
          const float* __restrict__ conv_b, const float* __restrict__ Wloc,
          const float* __restrict__ b_a, const float* __restrict__ Wk,
          const float* __restrict__ conv_w,
          float* __restrict__ bias, __bf16* __restrict__ wsB)
{
    const int tid = threadIdx.x;
    if (blockIdx.x < 64) {
        // ----- bias role -----
        int b = blockIdx.x;
        int u = tid & 127;
        int h = tid >> 7;                    // 0..1, K-half of 512
        const float* qr = query + b * QD_ + h * 512;
        const float* wq = Wq + (size_t)(h * 512) * U_ + u;
        float a0 = 0.f, a1 = 0.f, a2 = 0.f, a3 = 0.f;
        for (int e = 0; e < 512; e += 4) {
            a0 = fmaf(qr[e + 0], wq[(size_t)(e + 0) * U_], a0);
            a1 = fmaf(qr[e + 1], wq[(size_t)(e + 1) * U_], a1);
            a2 = fmaf(qr[e + 2], wq[(size_t)(e + 2) * U_], a2);
            a3 = fmaf(qr[e + 3], wq[(size_t)(e + 3) * U_], a3);
        }
        __shared__ float red[256];
        red[tid] = (a0 + a1) + (a2 + a3);
        __syncthreads();
        if (h == 0) {
            float s = red[u] + red[128 + u];
            float cb = 0.f;
            for (int f = 0; f < F_; ++f)
                cb = fmaf(conv_b[f], Wloc[f * U_ + u], cb);
            bias[b * U_ + u] = s + cb + b_a[u];
        }
    } else {
        // ----- wsB role -----
        int idx = (blockIdx.x - 64) * 256 + tid;     // 0 .. 17*8*64-1
        if (idx >= 17 * 8 * 64) return;
        int lane = idx & 63;
        int nt   = (idx >> 6) & 7;
        int kk   = idx >> 9;
        int n = nt * 16 + (lane & 15);
        int kbase = (lane >> 4) * 8;
        float vals[8];
        if (kk < 16) {
            #pragma unroll
            for (int j = 0; j < 8; ++j)
                vals[j] = Wk[(size_t)(kk * 32 + kbase + j) * U_ + n];
        } else {
            #pragma unroll
            for (int j = 0; j < 8; ++j) {
                int k = kbase + j;
                float s = 0.f;
                if (k < KW_)
                    for (int f = 0; f < F_; ++f)
                        s = fmaf(conv_w[k * F_ + f], Wloc[f * U_ + n], s);
                vals[j] = s;
            }
        }
        __bf16* dst = wsB + (size_t)idx * 8;
        #pragma unroll
        for (int j = 0; j < 8; ++j) dst[j] = f2bf(vals[j]);
    }
}

// ---------------------------------------------------------------------------
// lsa_energy: energy[b,t] = v . tanh(memory[b,t,:]@Wk + prevwin@CW + bias[b,:])
// grid: 64*16 blocks of 256 threads; block = 128 rows; wave = 32 rows x 128 U.
// Fully-masked tiles (t0 >= seqlen[b]) exit before touching memory.
// Distance-1 software pipeline on K; plain (cached) loads — nt hint removed:
// x/y load pairs rely on L1 line reuse which evict-first policy weakens.
// ---------------------------------------------------------------------------
__global__ __launch_bounds__(256, 4)
void lsa_energy(const float* __restrict__ mem, const float* __restrict__ prev,
                const float* __restrict__ bias, const bf16x8* __restrict__ wsB,
                const float* __restrict__ v_a, const int* __restrict__ seqlen,
                float* __restrict__ energy)
{
    const int tile = blockIdx.x & 15;
    const int b    = blockIdx.x >> 4;
    const int t0   = tile * 128;
    if (t0 >= seqlen[b]) return;         // masked tile: softmax forces -1e9

    const int tid  = threadIdx.x;
    const int wave = tid >> 6;
    const int lane = tid & 63;
    const int l15  = lane & 15;
    const int quad = lane >> 4;

    __shared__ float lds_prev[160];      // prev[b, t0-15+i], zero-padded
    __shared__ float lds_bias[U_];
    __shared__ float lds_v[U_];

    if (tid < 160) {
        int t = t0 - 15 + tid;
        float v = 0.f;
        if (tid < 158 && t >= 0 && t < T_) v = prev[b * T_ + t];
        lds_prev[tid] = v;
    }
    if (tid < U_)                 lds_bias[tid] = bias[b * U_ + tid];
    if (tid >= U_ && tid < 2*U_)  lds_v[tid - U_] = v_a[tid - U_];
    __syncthreads();

    f32x4 acc[2][8];
    #pragma unroll
    for (int s = 0; s < 2; ++s)
        #pragma unroll
        for (int n = 0; n < 8; ++n) acc[s][n] = (f32x4){0.f, 0.f, 0.f, 0.f};

    const int rl0 = wave * 32 + l15;                      // local row, s=0
    int r0 = t0 + rl0;      if (r0 > T_ - 1) r0 = T_ - 1; // clamp tail tile
    int r1 = t0 + rl0 + 16; if (r1 > T_ - 1) r1 = T_ - 1;
    const float* pA0 = mem + ((size_t)b * T_ + r0) * ENC_ + quad * 8;
    const float* pA1 = mem + ((size_t)b * T_ + r1) * ENC_ + quad * 8;
    const bf16x8* bp = wsB + lane;                        // bump 8*64 per kk

    // pipeline prologue: kk=0 A-tile
    f32x4 x0 = *(const f32x4*)pA0;
    f32x4 y0 = *(const f32x4*)(pA0 + 4);
    f32x4 x1 = *(const f32x4*)pA1;
    f32x4 y1 = *(const f32x4*)(pA1 + 4);

    for (int kk = 0; kk < 16; ++kk) {
        // B group 1 loads first (L2 hits, short latency)
        bf16x8 bfr[4];
        #pragma unroll
        for (int n = 0; n < 4; ++n) bfr[n] = bp[n * 64];

        // prefetch next A-tile (HBM, long latency) before any MFMA
        f32x4 nx0, ny0, nx1, ny1;
        if (kk < 15) {
            const float* q0 = pA0 + (kk + 1) * 32;
            const float* q1 = pA1 + (kk + 1) * 32;
            nx0 = *(const f32x4*)q0;
            ny0 = *(const f32x4*)(q0 + 4);
            nx1 = *(const f32x4*)q1;
            ny1 = *(const f32x4*)(q1 + 4);
        }

        bf16x8 a0, a1;
        #pragma unroll
        for (int j = 0; j < 4; ++j) { a0[j] = f2bf(x0[j]); a0[4+j] = f2bf(y0[j]); }
        #pragma unroll
        for (int j = 0; j < 4; ++j) { a1[j] = f2bf(x1[j]); a1[4+j] = f2bf(y1[j]); }

        #pragma unroll
        for (int n = 0; n < 4; ++n) {
            acc[0][n] = __builtin_amdgcn_mfma_f32_16x16x32_bf16(a0, bfr[n], acc[0][n], 0, 0, 0);
            acc[1][n] = __builtin_amdgcn_mfma_f32_16x16x32_bf16(a1, bfr[n], acc[1][n], 0, 0, 0);
        }
        #pragma unroll
        for (int n = 0; n < 4; ++n) bfr[n] = bp[(n + 4) * 64];
        #pragma unroll
        for (int n = 0; n < 4; ++n) {
            acc[0][n+4] = __builtin_amdgcn_mfma_f32_16x16x32_bf16(a0, bfr[n], acc[0][n+4], 0, 0, 0);
            acc[1][n+4] = __builtin_amdgcn_mfma_f32_16x16x32_bf16(a1, bfr[n], acc[1][n+4], 0, 0, 0);
        }
        bp += 8 * 64;
        x0 = nx0; y0 = ny0; x1 = nx1; y1 = ny1;
    }

    // location conv as one K=32 MFMA step (CW slice kk=16); A from prev window
    {
        bf16x8 a0, a1;
        int base = rl0 + quad * 8;   // lds_prev idx = row_local + k
        #pragma unroll
        for (int j = 0; j < 8; ++j) a0[j] = f2bf(lds_prev[base + j]);
        #pragma unroll
        for (int j = 0; j < 8; ++j) a1[j] = f2bf(lds_prev[base + 16 + j]);
        bf16x8 bfr[4];
        #pragma unroll
        for (int n = 0; n < 4; ++n) bfr[n] = bp[n * 64];
        #pragma unroll
        for (int n = 0; n < 4; ++n) {
            acc[0][n] = __builtin_amdgcn_mfma_f32_16x16x32_bf16(a0, bfr[n], acc[0][n], 0, 0, 0);
            acc[1][n] = __builtin_amdgcn_mfma_f32_16x16x32_bf16(a1, bfr[n], acc[1][n], 0, 0, 0);
        }
        #pragma unroll
        for (int n = 0; n < 4; ++n) bfr[n] = bp[(n + 4) * 64];
        #pragma unroll
        for (int n = 0; n < 4; ++n) {
            acc[0][n+4] = __builtin_amdgcn_mfma_f32_16x16x32_bf16(a0, bfr[n], acc[0][n+4], 0, 0, 0);
            acc[1][n+4] = __builtin_amdgcn_mfma_f32_16x16x32_bf16(a1, bfr[n], acc[1][n+4], 0, 0, 0);
        }
    }

    // epilogue: tanh(x + bias) * v, dot over 128 cols
    float part[2][4] = {{0.f,0.f,0.f,0.f},{0.f,0.f,0.f,0.f}};
    #pragma unroll
    for (int n = 0; n < 8; ++n) {
        float bb = lds_bias[n * 16 + l15];
        float vv = lds_v[n * 16 + l15];
        #pragma unroll
        for (int s = 0; s < 2; ++s)
            #pragma unroll
            for (int i = 0; i < 4; ++i) {
                float x  = acc[s][n][i] + bb;
                float ax = __builtin_fabsf(x);
                float e  = __expf(-2.f * ax);
                float th = (1.f - e) / (1.f + e);     // tanh(|x|), no overflow
                part[s][i] += (x < 0.f ? -th : th) * vv;
            }
    }
    #pragma unroll
    for (int s = 0; s < 2; ++s)
        #pragma unroll
        for (int i = 0; i < 4; ++i) {
            float p = part[s][i];
            p += __shfl_xor(p, 1);
            p += __shfl_xor(p, 2);
            p += __shfl_xor(p, 4);
            p += __shfl_xor(p, 8);       // butterfly within 16-lane group
            part[s][i] = p;
        }
    if (l15 == 0) {
        #pragma unroll
        for (int s = 0; s < 2; ++s)
            #pragma unroll
            for (int i = 0; i < 4; ++i) {
                int t = t0 + wave * 32 + s * 16 + quad * 4 + i;
                if (t < T_) energy[b * T_ + t] = part[s][i];
            }
    }
}

// ---------------------------------------------------------------------------
// softmax over T with length mask; out[0] = alignments, out[1] = align + prev.
// Energy was written into out[0] region as scratch; in-place per block.
// ---------------------------------------------------------------------------
__global__ __launch_bounds__(256)
void lsa_softmax(const float* __restrict__ prev, const int* __restrict__ seqlen,
                 float* __restrict__ out)
{
    int b = blockIdx.x;
    int tid = threadIdx.x;
    int len = seqlen[b];
    float e[8];
    float m = -1e30f;
    #pragma unroll
    for (int i = 0; i < 8; ++i) {
        int t = tid + i * 256;
        float x = -1e30f;
        if (t < T_) {
            x = out[b * T_ + t];
            if (t >= len) x = -1e9f;
        }
        e[i] = x;
        m = fmaxf(m, x);
    }
    #pragma unroll
    for (int off = 32; off >= 1; off >>= 1) m = fmaxf(m, __shfl_xor(m, off));
    __shared__ float wmax[4], wsum[4];
    if ((tid & 63) == 0) wmax[tid >> 6] = m;
    __syncthreads();
    m = fmaxf(fmaxf(wmax[0], wmax[1]), fmaxf(wmax[2], wmax[3]));
    float s = 0.f;
    #pragma unroll
    for (int i = 0; i < 8; ++i) {
        float p = __expf(e[i] - m);
        if (tid + i * 256 >= T_) p = 0.f;
        e[i] = p;
        s += p;
    }
    #pragma unroll
    for (int off = 32; off >= 1; off >>= 1) s += __shfl_xor(s, off);
    if ((tid & 63) == 0) wsum[tid >> 6] = s;
    __syncthreads();
    s = wsum[0] + wsum[1] + wsum[2] + wsum[3];
    float inv = 1.f / s;
    #pragma unroll
    for (int i = 0; i < 8; ++i) {
        int t = tid + i * 256;
        if (t < T_) {
            float a = e[i] * inv;
            out[b * T_ + t] = a;
            out[(size_t)B_ * T_ + b * T_ + t] = a + prev[b * T_ + t];
        }
    }
}

// ---------------------------------------------------------------------------
extern "C" void kernel_launch(void* const* d_in, const int* in_sizes, int n_in,
                              void* d_out, int out_size, void* d_ws, size_t ws_size,
                              hipStream_t stream)
{
    const float* query  = (const float*)d_in[0];
    const float* prev   = (const float*)d_in[1];
    const float* memory = (const float*)d_in[2];
    const int*   mlen   = (const int*)d_in[3];
    const float* Wq     = (const float*)d_in[4];
    const float* Wk     = (const float*)d_in[5];
    const float* conv_w = (const float*)d_in[6];
    const float* conv_b = (const float*)d_in[7];
    const float* Wloc   = (const float*)d_in[8];
    const float* v_a    = (const float*)d_in[9];
    const float* b_a    = (const float*)d_in[10];
    float* out = (float*)d_out;

    // ws: [wsB: 17*8*64*8 bf16 = 139264 B][bias: 64*128 f32 = 32768 B]
    __bf16* wsB  = (__bf16*)d_ws;
    float*  bias = (float*)((char*)d_ws + (size_t)17 * 8 * 64 * 8 * 2);

    prep<<<dim3(98), dim3(256), 0, stream>>>(query, Wq, conv_b, Wloc, b_a,
                                             Wk, conv_w, bias, wsB);
    lsa_energy<<<dim3(64 * 16), dim3(256), 0, stream>>>(memory, prev, bias,
                                                        (const bf16x8*)wsB,
                                                        v_a, mlen, out);
    lsa_softmax<<<dim3(64), dim3(256), 0, stream>>>(prev, mlen, out);
}